// Round 6
// baseline (1396.470 us; speedup 1.0000x reference)
//
#include <hip/hip_runtime.h>
#include <cstdint>
#include <cstddef>

#define UNITS 25
#define IN_DIM 64
#define BATCH 256
#define SEQ 2048
#define BT (BATCH * SEQ)
#define L2E 1.442695040888963f

typedef _Float16 h2t __attribute__((ext_vector_type(2)));

#define R13(M) M(0) M(1) M(2) M(3) M(4) M(5) M(6) M(7) M(8) M(9) M(10) M(11) M(12)

// f32 pair -> packed f16 (v_cvt_pkrtz_f16_f32)
__device__ __forceinline__ unsigned pk16(float lo, float hi) {
    return __builtin_bit_cast(unsigned, __builtin_amdgcn_cvt_pkrtz(lo, hi));
}
__device__ __forceinline__ float lo16(unsigned u) {
    return (float)__builtin_bit_cast(h2t, u).x;
}
__device__ __forceinline__ float hi16(unsigned u) {
    return (float)__builtin_bit_cast(h2t, u).y;
}
// 2-way f16 dot with f32 accumulate (v_dot2_f32_f16)
__device__ __forceinline__ float fdot2_(unsigned w, unsigned h, float c) {
#if __has_builtin(__builtin_amdgcn_fdot2)
    return __builtin_amdgcn_fdot2(__builtin_bit_cast(h2t, w),
                                  __builtin_bit_cast(h2t, h), c, false);
#else
    h2t W = __builtin_bit_cast(h2t, w), H = __builtin_bit_cast(h2t, h);
    return fmaf((float)W.x, (float)H.x, fmaf((float)W.y, (float)H.y, c));
#endif
}
// swap within lane pairs (0<->1,...): quad_perm(1,0,3,2)
__device__ __forceinline__ float dswap(float v) {
    return __int_as_float(__builtin_amdgcn_mov_dpp(__float_as_int(v), 0xB1, 0xF, 0xF, true));
}
// every lane gets quad-position-2's value: quad_perm(2,2,2,2)
__device__ __forceinline__ float dpp2(float v) {
    return __int_as_float(__builtin_amdgcn_mov_dpp(__float_as_int(v), 0xAA, 0xF, 0xF, true));
}
__device__ __forceinline__ float sig_raw(float a) {      // 1/(1+exp2(a))
    return __builtin_amdgcn_rcpf(1.0f + __builtin_amdgcn_exp2f(a));
}
__device__ __forceinline__ float tanh5(float c) {        // tanh(c), c unscaled
    return fmaf(2.0f, __builtin_amdgcn_rcpf(
        1.0f + __builtin_amdgcn_exp2f(-2.0f * L2E * c)), -1.0f);
}
// pinned global load: volatile asm result cannot be rematerialized
__device__ __forceinline__ unsigned ldpin(const unsigned* p) {
    unsigned v;
    asm volatile("global_load_dword %0, %1, off\n\ts_waitcnt vmcnt(0)"
                 : "=v"(v) : "v"(p) : "memory");
    return v;
}
// workgroup barrier WITHOUT vmcnt drain: LDS writes retired (lgkmcnt), but
// in-flight HBM prefetch loads stay outstanding across the barrier.
__device__ __forceinline__ void wave_barrier() {
    asm volatile("s_waitcnt lgkmcnt(0)\n\ts_barrier" ::: "memory");
}

// Column order (shared prep/proj/scan): c<50 = pass A (even=i, odd=f);
// c>=50 = pass B (even=c-gate[tanh], odd=o). unit u = ((c%50)>>1).
// Activation scale folded into weights/biases: tanh cols -2*L2E, else -L2E.

__device__ unsigned g_w1[13 * 100];    // layer-1 recurrent, f16 k-pairs, scaled
__device__ unsigned g_wx[13 * 100];    // layer-2 input (h1) weights
__device__ unsigned g_wh[13 * 100];    // layer-2 recurrent
__device__ unsigned g_wo[13];          // head weights, f16 pairs, scaled by -L2E
__device__ unsigned g_Wp16[100 * 32];  // proj weights: [c][kpair] f16 pairs, scaled
__device__ float    g_bp[100];         // proj bias [c], scaled

// ---------------------------------------------------------------------------
__global__ void prep_kernel(const float* __restrict__ l1_Whi, const float* __restrict__ l1_Whf,
                            const float* __restrict__ l1_Whc, const float* __restrict__ l1_Who,
                            const float* __restrict__ l1_Wxi, const float* __restrict__ l1_Wxf,
                            const float* __restrict__ l1_Wxc, const float* __restrict__ l1_Wxo,
                            const float* __restrict__ l1_bi,  const float* __restrict__ l1_bf,
                            const float* __restrict__ l1_bc,  const float* __restrict__ l1_bo,
                            const float* __restrict__ l2_Wxi, const float* __restrict__ l2_Wxf,
                            const float* __restrict__ l2_Wxc, const float* __restrict__ l2_Wxo,
                            const float* __restrict__ l2_Whi, const float* __restrict__ l2_Whf,
                            const float* __restrict__ l2_Whc, const float* __restrict__ l2_Who,
                            const float* __restrict__ Wout) {
    const int c = threadIdx.x;
    if (c < 100) {
        const int half = (c >= 50);
        const int l = half ? c - 50 : c;
        const int u = l >> 1;
        const int par = l & 1;
        const float s = (half && !par) ? (-2.0f * L2E) : (-L2E);
        const float* W1 = half ? (par ? l1_Who : l1_Whc) : (par ? l1_Whf : l1_Whi);
        const float* WX = half ? (par ? l2_Wxo : l2_Wxc) : (par ? l2_Wxf : l2_Wxi);
        const float* WH = half ? (par ? l2_Who : l2_Whc) : (par ? l2_Whf : l2_Whi);
        const float* WI = half ? (par ? l1_Wxo : l1_Wxc) : (par ? l1_Wxf : l1_Wxi);
        const float* bI = half ? (par ? l1_bo  : l1_bc)  : (par ? l1_bf  : l1_bi);
        for (int i = 0; i < 13; ++i) {
            const int k0 = 2 * i, k1 = 2 * i + 1;
            const float a1 = s * W1[k0 * UNITS + u];
            const float b1 = (k1 < UNITS) ? s * W1[k1 * UNITS + u] : 0.f;
            g_w1[i * 100 + c] = pk16(a1, b1);
            const float ax = s * WX[k0 * UNITS + u];
            const float bx = (k1 < UNITS) ? s * WX[k1 * UNITS + u] : 0.f;
            g_wx[i * 100 + c] = pk16(ax, bx);
            const float ah = s * WH[k0 * UNITS + u];
            const float bh = (k1 < UNITS) ? s * WH[k1 * UNITS + u] : 0.f;
            g_wh[i * 100 + c] = pk16(ah, bh);
        }
        for (int kp = 0; kp < 32; ++kp)
            g_Wp16[c * 32 + kp] = pk16(s * WI[(2 * kp) * UNITS + u],
                                       s * WI[(2 * kp + 1) * UNITS + u]);
        g_bp[c] = s * bI[u];
    }
    if (c == 100) {
        for (int i = 0; i < 13; ++i) {
            const int k1 = 2 * i + 1;
            g_wo[i] = pk16(-L2E * Wout[2 * i],
                           (k1 < UNITS) ? -L2E * Wout[k1] : 0.f);
        }
    }
}

// ---------------------------------------------------------------------------
// proj: pre2h[row][c] = pk16(scaled pre col c, col c+50).  2 rows/thread,
// f16-pair weights in LDS (uint4 broadcast reads), dot2 math, f16-pair out.
// ---------------------------------------------------------------------------
__global__ __launch_bounds__(256, 2)
void proj_kernel(const float* __restrict__ x, unsigned* __restrict__ pre2h) {
    __shared__ unsigned wls[100 * 32];
    __shared__ float bls[100];
    for (int i = threadIdx.x; i < 3200; i += 256) wls[i] = g_Wp16[i];
    if (threadIdx.x < 100) bls[threadIdx.x] = g_bp[threadIdx.x];
    __syncthreads();

    const int r0 = blockIdx.x * 512 + threadIdx.x;   // 1024 blocks cover BT
    const int r1 = r0 + 256;

    uint4 xp[2][8];                                  // x rows as f16 k-pairs
    #pragma unroll
    for (int r = 0; r < 2; ++r) {
        const float4* xr = (const float4*)(x + (size_t)(r ? r1 : r0) * IN_DIM);
        #pragma unroll
        for (int j = 0; j < 8; ++j) {
            const float4 a = xr[2 * j], b = xr[2 * j + 1];
            xp[r][j] = make_uint4(pk16(a.x, a.y), pk16(a.z, a.w),
                                  pk16(b.x, b.y), pk16(b.z, b.w));
        }
    }
    unsigned* o0 = pre2h + (size_t)r0 * 50;
    unsigned* o1 = pre2h + (size_t)r1 * 50;

    #pragma unroll 1
    for (int c = 0; c < 50; ++c) {
        const uint4* wA = (const uint4*)(wls + c * 32);          // col c
        const uint4* wB = (const uint4*)(wls + (c + 50) * 32);   // col c+50
        float aA0 = bls[c],      aA1 = 0.f, bA0 = 0.f, bA1 = 0.f;
        float aB0 = bls[c + 50], aB1 = 0.f, bB0 = 0.f, bB1 = 0.f;
        float cA0 = bls[c],      cA1 = 0.f, dA0 = 0.f, dA1 = 0.f;
        float cB0 = bls[c + 50], cB1 = 0.f, dB0 = 0.f, dB1 = 0.f;
        #pragma unroll
        for (int j = 0; j < 8; ++j) {
            const uint4 wa = wA[j], wb = wB[j];
            const uint4 x0 = xp[0][j], x1 = xp[1][j];
            aA0 = fdot2_(wa.x, x0.x, aA0); bA0 = fdot2_(wa.y, x0.y, bA0);
            aA1 = fdot2_(wa.z, x0.z, aA1); bA1 = fdot2_(wa.w, x0.w, bA1);
            aB0 = fdot2_(wb.x, x0.x, aB0); bB0 = fdot2_(wb.y, x0.y, bB0);
            aB1 = fdot2_(wb.z, x0.z, aB1); bB1 = fdot2_(wb.w, x0.w, bB1);
            cA0 = fdot2_(wa.x, x1.x, cA0); dA0 = fdot2_(wa.y, x1.y, dA0);
            cA1 = fdot2_(wa.z, x1.z, cA1); dA1 = fdot2_(wa.w, x1.w, dA1);
            cB0 = fdot2_(wb.x, x1.x, cB0); dB0 = fdot2_(wb.y, x1.y, dB0);
            cB1 = fdot2_(wb.z, x1.z, cB1); dB1 = fdot2_(wb.w, x1.w, dB1);
        }
        o0[c] = pk16((aA0 + aA1) + (bA0 + bA1), (aB0 + aB1) + (bB0 + bB1));
        o1[c] = pk16((cA0 + cA1) + (dA0 + dA1), (cB0 + cB1) + (dB0 + dB1));
    }
}

// ---------------------------------------------------------------------------
// scan: 1 batch/block, 128 threads = 2 waves (2 SIMDs), layer-pipelined:
//   wave0: L1(t) + head(t-2);  wave1: L2(t-1).
// h1/h2 as packed-f16 pairs in 2-slot LDS rings; 1 lgkm-only barrier/step
// (prefetch loads stay in flight across it). Interval k (k=0..SEQ+1):
//   w0: head reads h2slot[(k-2)&1]; writes h1(k) -> h1slot[k&1]
//   w1: reads h1slot[(k-1)&1]; writes h2(k-1) -> h2slot[(k-1)&1]
// All RAW pairs separated by exactly one barrier; WAR pairs by two. Verified.
// ---------------------------------------------------------------------------
__global__ __attribute__((amdgpu_waves_per_eu(1, 1))) __launch_bounds__(128)
void lstm_scan_kernel(const unsigned* __restrict__ pre2h,
                      const float* __restrict__ l2_bi, const float* __restrict__ l2_bf,
                      const float* __restrict__ l2_bc, const float* __restrict__ l2_bo,
                      const float* __restrict__ bout,
                      float* __restrict__ out) {
    const int tid  = threadIdx.x;
    const int b    = blockIdx.x;
    const int lane = tid & 63;
    const int wid  = tid >> 6;
    const int lc   = (lane < 50) ? lane : 49;  // junk lanes compute, never read
    const int uu   = lc >> 1;
    const bool odd = (lane & 1);

    __shared__ unsigned h1s[2][16];
    __shared__ unsigned h2s[2][16];
    if (tid < 32) (&h1s[0][0])[tid] = 0u;
    else if (tid < 64) (&h2s[0][0])[tid - 32] = 0u;
    __syncthreads();

    const float tA = odd ? 1.0f : 2.0f;      // pass-B act: even=tanh, odd=sig
    const float tC = odd ? 0.0f : -1.0f;
    const bool wr = ((lane & 3) == 0) && (lane < 52);   // 13 writer lanes
    const int  q  = lane >> 2;

    if (wid == 0) {
        // ================= wave 0: layer 1 + head =================
        #define LW0(i) const unsigned w1A_##i = ldpin(g_w1 + (i)*100 + lc);      \
                       const unsigned w1B_##i = ldpin(g_w1 + (i)*100 + 50 + lc); \
                       const unsigned wo_##i  = ldpin(g_wo + (i));
        R13(LW0)
        #undef LW0
        const float boutv = bout[0] * (-L2E);
        float c1 = 0.f;
        const unsigned* prow = pre2h + (size_t)b * SEQ * 50 + lc;
        const unsigned p0 = prow[0];
        float aA = lo16(p0), aB = hi16(p0);   // carried F1 acc (h1(-1)=0)
        unsigned pn1 = prow[50], pn2 = prow[100];
        float* orow = out + (size_t)b * SEQ;

        #pragma unroll 1
        for (int k = 0; k < SEQ + 2; ++k) {
            if (k >= 2) {                     // ---- head(t = k-2)
                const unsigned* hb = &h2s[(k - 2) & 1][0];
                const uint4 H0 = ((const uint4*)hb)[0];
                const uint4 H1 = ((const uint4*)hb)[1];
                const uint4 H2 = ((const uint4*)hb)[2];
                const unsigned H3 = hb[12];
                float hp = boutv;
                hp = fdot2_(wo_0,  H0.x, hp); hp = fdot2_(wo_1,  H0.y, hp);
                hp = fdot2_(wo_2,  H0.z, hp); hp = fdot2_(wo_3,  H0.w, hp);
                hp = fdot2_(wo_4,  H1.x, hp); hp = fdot2_(wo_5,  H1.y, hp);
                hp = fdot2_(wo_6,  H1.z, hp); hp = fdot2_(wo_7,  H1.w, hp);
                hp = fdot2_(wo_8,  H2.x, hp); hp = fdot2_(wo_9,  H2.y, hp);
                hp = fdot2_(wo_10, H2.z, hp); hp = fdot2_(wo_11, H2.w, hp);
                hp = fdot2_(wo_12, H3,   hp);
                if (lane == 0) orow[k - 2] = sig_raw(hp);
            }
            if (k < SEQ) {                    // ---- L1(t = k)
                const float avA = sig_raw(aA);
                const float avB = fmaf(tA, sig_raw(aB), tC);
                const float fv = dswap(avA);
                const float ov = dswap(avB);
                c1 = fmaf(avB, avA, fv * c1);               // even lanes valid
                const float h1v = ov * tanh5(c1);
                const unsigned m1 = pk16(h1v, dpp2(h1v));   // lane 4q: pair q
                unsigned* hw = &h1s[k & 1][0];
                if (wr) hw[q] = m1;
                const uint4 S0 = ((const uint4*)hw)[0];     // own read-back
                const uint4 S1 = ((const uint4*)hw)[1];
                const uint4 S2 = ((const uint4*)hw)[2];
                const unsigned S3 = hw[12];
                const unsigned s1_0 = S0.x, s1_1 = S0.y, s1_2  = S0.z, s1_3  = S0.w;
                const unsigned s1_4 = S1.x, s1_5 = S1.y, s1_6  = S1.z, s1_7  = S1.w;
                const unsigned s1_8 = S2.x, s1_9 = S2.y, s1_10 = S2.z, s1_11 = S2.w;
                const unsigned s1_12 = S3;
                const unsigned pw = pn1;
                pn1 = pn2;
                const int ni = (k + 3 < SEQ) ? (k + 3) : (SEQ - 1);
                pn2 = prow[(size_t)ni * 50];                // 2-interval lead
                float naA = lo16(pw), naB = hi16(pw);
                #define DN(i) naA = fdot2_(w1A_##i, s1_##i, naA); \
                              naB = fdot2_(w1B_##i, s1_##i, naB);
                R13(DN)
                #undef DN
                aA = naA; aB = naB;
            }
            wave_barrier();
        }
    } else {
        // ================= wave 1: layer 2 =================
        #define LW1(i) const unsigned wxA_##i = ldpin(g_wx + (i)*100 + lc);      \
                       const unsigned wxB_##i = ldpin(g_wx + (i)*100 + 50 + lc); \
                       const unsigned whA_##i = ldpin(g_wh + (i)*100 + lc);      \
                       const unsigned whB_##i = ldpin(g_wh + (i)*100 + 50 + lc);
        R13(LW1)
        #undef LW1
        const float b2A = (odd ? l2_bf[uu] : l2_bi[uu]) * (-L2E);
        const float b2B = odd ? (l2_bo[uu] * (-L2E)) : (l2_bc[uu] * (-2.0f * L2E));
        float c2 = 0.f;
        #define DS2(i) unsigned s2_##i = 0u;     // own h2 broadcast (h2(-1)=0)
        R13(DS2)
        #undef DS2

        #pragma unroll 1
        for (int k = 0; k < SEQ + 2; ++k) {
            if (k >= 1 && k <= SEQ) {         // ---- L2(t = k-1)
                const int t = k - 1;
                const unsigned* sb = &h1s[t & 1][0];
                const uint4 S0 = ((const uint4*)sb)[0];
                const uint4 S1 = ((const uint4*)sb)[1];
                const uint4 S2 = ((const uint4*)sb)[2];
                const unsigned S3 = sb[12];
                const unsigned s1_0 = S0.x, s1_1 = S0.y, s1_2  = S0.z, s1_3  = S0.w;
                const unsigned s1_4 = S1.x, s1_5 = S1.y, s1_6  = S1.z, s1_7  = S1.w;
                const unsigned s1_8 = S2.x, s1_9 = S2.y, s1_10 = S2.z, s1_11 = S2.w;
                const unsigned s1_12 = S3;
                float xA = b2A, xB = b2B, hA = 0.f, hB = 0.f;
                #define D2(i) xA = fdot2_(wxA_##i, s1_##i, xA); \
                              xB = fdot2_(wxB_##i, s1_##i, xB); \
                              hA = fdot2_(whA_##i, s2_##i, hA); \
                              hB = fdot2_(whB_##i, s2_##i, hB);
                R13(D2)
                #undef D2
                const float avA2 = sig_raw(xA + hA);
                const float avB2 = fmaf(tA, sig_raw(xB + hB), tC);
                const float fv2 = dswap(avA2);
                const float ov2 = dswap(avB2);
                c2 = fmaf(avB2, avA2, fv2 * c2);
                const float h2v = ov2 * tanh5(c2);
                const unsigned m2 = pk16(h2v, dpp2(h2v));
                unsigned* hw = &h2s[t & 1][0];
                if (wr) hw[q] = m2;
                const uint4 R0 = ((const uint4*)hw)[0];     // own read-back
                const uint4 R1 = ((const uint4*)hw)[1];
                const uint4 R2 = ((const uint4*)hw)[2];
                const unsigned R3 = hw[12];
                s2_0 = R0.x; s2_1 = R0.y; s2_2  = R0.z; s2_3  = R0.w;
                s2_4 = R1.x; s2_5 = R1.y; s2_6  = R1.z; s2_7  = R1.w;
                s2_8 = R2.x; s2_9 = R2.y; s2_10 = R2.z; s2_11 = R2.w;
                s2_12 = R3;
            }
            wave_barrier();
        }
    }
}

// ---------------------------------------------------------------------------
extern "C" void kernel_launch(void* const* d_in, const int* in_sizes, int n_in,
                              void* d_out, int out_size, void* d_ws, size_t ws_size,
                              hipStream_t stream) {
    const float* x      = (const float*)d_in[0];
    const float* Wout   = (const float*)d_in[1];
    const float* bout   = (const float*)d_in[2];
    const float* l1_Wxi = (const float*)d_in[3];
    const float* l1_bi  = (const float*)d_in[4];
    const float* l1_Whi = (const float*)d_in[5];
    const float* l1_Wxf = (const float*)d_in[6];
    const float* l1_bf  = (const float*)d_in[7];
    const float* l1_Whf = (const float*)d_in[8];
    const float* l1_Wxc = (const float*)d_in[9];
    const float* l1_bc  = (const float*)d_in[10];
    const float* l1_Whc = (const float*)d_in[11];
    const float* l1_Wxo = (const float*)d_in[12];
    const float* l1_bo  = (const float*)d_in[13];
    const float* l1_Who = (const float*)d_in[14];
    const float* l2_Wxi = (const float*)d_in[15];
    const float* l2_bi  = (const float*)d_in[16];
    const float* l2_Whi = (const float*)d_in[17];
    const float* l2_Wxf = (const float*)d_in[18];
    const float* l2_bf  = (const float*)d_in[19];
    const float* l2_Whf = (const float*)d_in[20];
    const float* l2_Wxc = (const float*)d_in[21];
    const float* l2_bc  = (const float*)d_in[22];
    const float* l2_Whc = (const float*)d_in[23];
    const float* l2_Wxo = (const float*)d_in[24];
    const float* l2_bo  = (const float*)d_in[25];
    const float* l2_Who = (const float*)d_in[26];
    float* out = (float*)d_out;

    unsigned* pre2h = (unsigned*)d_ws;   // [BT][50] u32 = 105 MB

    prep_kernel<<<1, 128, 0, stream>>>(
        l1_Whi, l1_Whf, l1_Whc, l1_Who,
        l1_Wxi, l1_Wxf, l1_Wxc, l1_Wxo,
        l1_bi, l1_bf, l1_bc, l1_bo,
        l2_Wxi, l2_Wxf, l2_Wxc, l2_Wxo,
        l2_Whi, l2_Whf, l2_Whc, l2_Who,
        Wout);
    proj_kernel<<<BT / 512, 256, 0, stream>>>(x, pre2h);
    lstm_scan_kernel<<<BATCH, 128, 0, stream>>>(
        pre2h, l2_bi, l2_bf, l2_bc, l2_bo, bout, out);
}